// Round 6
// baseline (447.274 us; speedup 1.0000x reference)
//
#include <hip/hip_runtime.h>
#include <hip/hip_bf16.h>
#include <cstdint>

// ---------------- problem constants ----------------
#define NN      8192      // nodes
#define OF      64        // out features
#define HWROWS  80        // 64 h-cols + 1 e-col + 15 zero rows (bf16 plane)
#define RSTR    84        // LDS reduce stride (2-way aliasing only -> free)

// ---------------- ws layout (bytes) ----------------
#define OFF_HW  0                         // HW 80x8192 u16 = 1310720

typedef __attribute__((ext_vector_type(8))) short  s16x8;
typedef __attribute__((ext_vector_type(4))) float  f32x4;

__device__ __forceinline__ unsigned short f2bf(float f) {
  unsigned int u = __float_as_uint(f);
  unsigned int r = (u + 0x7FFFu + ((u >> 16) & 1u)) >> 16;   // RNE
  return (unsigned short)r;
}

// ---------------- k1: h = X @ W (LDS-tiled fp32) -> fused e/HW write -------
// bf16 B is safe: outputs are ~4096-term softmax-weighted means; RNE errors
// average down ~1/sqrt(4096).
__global__ __launch_bounds__(256) void k1_hw(const float* __restrict__ X,
                                             const float* __restrict__ W,
                                             const float* __restrict__ att,
                                             unsigned short* __restrict__ HW) {
  __shared__ float xs[16 * 516];     // odd 16B-segment stride
  __shared__ float ws[64 * 68];
  int t = threadIdx.x;
  int rb = blockIdx.x * 16;

  {
    const float4* src = (const float4*)(X + (size_t)rb * 512);
#pragma unroll
    for (int s = 0; s < 8; ++s) {
      int lid = s * 256 + t;
      int row = lid >> 7, kseg = lid & 127;
      *(float4*)&xs[row * 516 + kseg * 4] = src[row * 128 + kseg];
    }
  }

  int row = t >> 4, tx = t & 15;     // thread: 1 row x 4 cols
  float4 acc = {0.f, 0.f, 0.f, 0.f};
  for (int kc = 0; kc < 8; ++kc) {
    __syncthreads();
#pragma unroll
    for (int s = 0; s < 4; ++s) {
      int lid = s * 256 + t;
      int k = lid >> 4, cs = lid & 15;
      *(float4*)&ws[k * 68 + cs * 4] =
          *(const float4*)(W + (size_t)(kc * 64 + k) * 64 + cs * 4);
    }
    __syncthreads();
#pragma unroll 16
    for (int k = 0; k < 64; ++k) {
      float x = xs[row * 516 + kc * 64 + k];
      float4 w4 = *(const float4*)&ws[k * 68 + tx * 4];
      acc.x += x * w4.x; acc.y += x * w4.y;
      acc.z += x * w4.z; acc.w += x * w4.w;
    }
  }

  float v = acc.x * att[64 + tx * 4]     + acc.y * att[64 + tx * 4 + 1] +
            acc.z * att[64 + tx * 4 + 2] + acc.w * att[64 + tx * 4 + 3];
#pragma unroll
  for (int m = 8; m > 0; m >>= 1) v += __shfl_xor(v, m, 64);
  float e = expf(v);                 // |r| <~ 21, no overflow

  int j = rb + row;
  unsigned short* hw = HW + j;
  float hv[4] = {acc.x, acc.y, acc.z, acc.w};
#pragma unroll
  for (int c = 0; c < 4; ++c)
    hw[(size_t)(tx * 4 + c) * NN] = f2bf(e * hv[c]);
  if (tx == 0) hw[(size_t)64 * NN] = f2bf(e);
  else         hw[(size_t)(64 + tx) * NN] = 0;   // zero rows 65..79
}

// ---------------- cvt: 8 int32 {0,1} -> 8 bf16 {0,1} (packed, 8 VALU) -----
__device__ __forceinline__ s16x8 cvt8(int4 a, int4 b) {
  union { unsigned u[4]; s16x8 v; } rr;
  rr.u[0] = (unsigned)(a.x | (a.y << 16)) * 0x3F80u;
  rr.u[1] = (unsigned)(a.z | (a.w << 16)) * 0x3F80u;
  rr.u[2] = (unsigned)(b.x | (b.y << 16)) * 0x3F80u;
  rr.u[3] = (unsigned)(b.z | (b.w << 16)) * 0x3F80u;
  return rr.v;
}

// ---------------- k3: full-K GAT row block, fused normalize+ELU -----------
// Grid 512, BM=16. Wave w owns K in [w*2048,(w+1)*2048): barrier-free K-loop,
// B fragments straight from L2 (16B/lane coalesced), A direct from HBM.
// Cross-wave LDS reduce, then normalize + ELU + coalesced out write.
__global__ __launch_bounds__(256, 2) void k3_gat(const int* __restrict__ A,
                                                 const unsigned short* __restrict__ HW,
                                                 float* __restrict__ out) {
  __shared__ float red[4 * 16 * RSTR];             // 21504 B

  int t = threadIdx.x;
  int lane = t & 63, w = t >> 6;
  int l15 = lane & 15, q = lane >> 4;
  int rowBase = blockIdx.x * 16;

  const int* ar = A + (size_t)(rowBase + l15) * NN + w * 2048 + q * 8;

  const unsigned short* bp[5];
#pragma unroll
  for (int tt = 0; tt < 5; ++tt)
    bp[tt] = HW + (size_t)(tt * 16 + l15) * NN + w * 2048 + q * 8;

  f32x4 acc[5];
#pragma unroll
  for (int tt = 0; tt < 5; ++tt) acc[tt] = 0.f;

#pragma unroll 2
  for (int step = 0; step < 32; ++step) {
    int4 a00 = *(const int4*)(ar);
    int4 a01 = *(const int4*)(ar + 4);
    int4 a02 = *(const int4*)(ar + 32);
    int4 a03 = *(const int4*)(ar + 36);
    ar += 64;

    s16x8 b0[5], b1[5];
#pragma unroll
    for (int tt = 0; tt < 5; ++tt) {
      b0[tt] = *(const s16x8*)(bp[tt]);
      b1[tt] = *(const s16x8*)(bp[tt] + 32);
      bp[tt] += 64;
    }

    s16x8 af0 = cvt8(a00, a01);
    s16x8 af1 = cvt8(a02, a03);

#pragma unroll
    for (int tt = 0; tt < 5; ++tt)
      acc[tt] = __builtin_amdgcn_mfma_f32_16x16x32_bf16(af0, b0[tt], acc[tt], 0, 0, 0);
#pragma unroll
    for (int tt = 0; tt < 5; ++tt)
      acc[tt] = __builtin_amdgcn_mfma_f32_16x16x32_bf16(af1, b1[tt], acc[tt], 0, 0, 0);
  }

  // cross-wave reduce: wave w stages its 16x80 tile (C/D: col=l15, row=q*4+rg)
  float* slab = red + w * 16 * RSTR;
#pragma unroll
  for (int tt = 0; tt < 5; ++tt)
#pragma unroll
    for (int rg = 0; rg < 4; ++rg)
      slab[(q * 4 + rg) * RSTR + tt * 16 + l15] = acc[tt][rg];
  __syncthreads();

  // sum 4 slabs -> fin (reuse slab 0); 1280 entries, 5 per thread
#pragma unroll
  for (int s = 0; s < 5; ++s) {
    int e = s * 256 + t;                 // 0..1279
    int r = e / 80, c = e - r * 80;
    float v = red[r * RSTR + c] + red[(16 + r) * RSTR + c] +
              red[(32 + r) * RSTR + c] + red[(48 + r) * RSTR + c];
    red[r * RSTR + c] = v;
  }
  __syncthreads();

  // normalize + ELU + write 16x64 outputs (coalesced)
#pragma unroll
  for (int i = 0; i < 4; ++i) {
    int g = i * 256 + t;                 // 0..1023
    int r = g >> 6, c = g & 63;
    float num = red[r * RSTR + c];
    float S   = red[r * RSTR + 64];
    float x = num / S;
    out[(size_t)(rowBase + r) * OF + c] = x > 0.f ? x : expm1f(x);
  }
}

extern "C" void kernel_launch(void* const* d_in, const int* in_sizes, int n_in,
                              void* d_out, int out_size, void* d_ws, size_t ws_size,
                              hipStream_t stream) {
  const float* X  = (const float*)d_in[0];   // 8192x512
  const int*   A  = (const int*)d_in[1];     // 8192x8192
  const float* W  = (const float*)d_in[2];   // 512x64
  const float* av = (const float*)d_in[3];   // 128x1
  float* out = (float*)d_out;

  char* ws = (char*)d_ws;
  unsigned short* HW = (unsigned short*)(ws + OFF_HW);

  k1_hw<<<NN / 16, 256, 0, stream>>>(X, W, av, HW);
  k3_gat<<<NN / 16, 256, 0, stream>>>(A, HW, out);
}